// Round 16
// baseline (1553.043 us; speedup 1.0000x reference)
//
#include <hip/hip_runtime.h>
#include <hip/hip_fp16.h>
#include <math.h>
#include <stdint.h>

typedef _Float16 f16;
typedef _Float16 h8 __attribute__((ext_vector_type(8)));
typedef float f4 __attribute__((ext_vector_type(4)));

#define TSTEPS 48

#define MFMA(a,b,c) __builtin_amdgcn_mfma_f32_16x16x32_f16((a),(b),(c),0,0,0)
// inline-asm MFMA with acc and B pinned to the AGPR half of the unified file
#define MFMA_AB(acc, a, b) \
  asm("v_mfma_f32_16x16x32_f16 %0, %1, %2, %0" : "+a"(acc) : "v"(a), "a"(b))

__device__ __forceinline__ float gelu_f(float x) {
  float ax = fabsf(x) * 0.7071067811865475f;
  float t = __builtin_amdgcn_rcpf(1.0f + 0.3275911f * ax);
  float poly = t * (0.254829592f + t * (-0.284496736f + t * (1.421413741f +
               t * (-1.453152027f + t * 1.061405429f))));
  float e = exp2f(-ax * ax * 1.4426950408889634f);
  float er = copysignf(1.0f - poly * e, x);
  return 0.5f * x * (1.0f + er);
}

__device__ __forceinline__ float tanh_f(float x) {
  float e = exp2f(x * 2.885390081777927f);
  return 1.0f - 2.0f * __builtin_amdgcn_rcpf(e + 1.0f);
}

__device__ __forceinline__ void gload_lds16(const void* g, void* l) {
  __builtin_amdgcn_global_load_lds(
      (const __attribute__((address_space(1))) void*)g,
      (__attribute__((address_space(3))) void*)l, 16, 0, 0);
}

// barrier that does NOT drain vmcnt (keeps weight prefetch depth alive).
// LDS visibility needs lgkmcnt(0) only; wbuf is wave-private so vmcnt-backed
// LDS writes never cross waves. (R15-verified primitive.)
__device__ __forceinline__ void barrier_lds() {
  asm volatile("s_waitcnt lgkmcnt(0)" ::: "memory");
  __builtin_amdgcn_s_barrier();
  __builtin_amdgcn_sched_barrier(0);
}

// ---------------- unified lane-linear weight prep (W1/W2/Wo/Wf2) ----------------
// Fragment (kk, cf): 16 cols c0=cf*16, 32 k's at kk*32. Lane ln holds 8 f16:
// dst[fragid*512 + ln*8 + e] = src[(kk*32 + (ln>>4)*8 + e) * N + cf*16 + (ln&15)]
__global__ void prep_lin(const float* __restrict__ src, f16* __restrict__ dst,
                         int Kreal, int N, int total) {
  int idx = blockIdx.x * 256 + threadIdx.x;
  if (idx >= total) return;
  int fragid = idx >> 9;
  int within = idx & 511;
  int ln = within >> 3, e = within & 7;
  int nfr = N >> 4;
  int kk = fragid / nfr, cf = fragid - kk * nfr;
  int k = kk * 32 + ((ln >> 4) << 3) + e;
  int n = (cf << 4) + (ln & 15);
  dst[idx] = (f16)((k < Kreal) ? src[k * N + n] : 0.f);
}

// ---------------- Wf1 chunk stream: 16 chunks of 16KB ----------------
// chunk c = (h*8 + kk): k-slice [32kk,+32) x cols [256h,+256) as 16 lane-linear
// 1KB frags (frag cf: cols [256h+16cf,+16)).
__global__ void prep_wf1c(const float* __restrict__ src, f16* __restrict__ dst) {
  int idx = blockIdx.x * 256 + threadIdx.x;    // 131072
  if (idx >= 131072) return;
  int f = idx >> 9, w = idx & 511;
  int ln = w >> 3, e = w & 7;
  int cf = f & 15, kk = (f >> 4) & 7, h = f >> 7;
  int n = 256 * h + 16 * cf + (ln & 15);
  int k = 32 * kk + 8 * (ln >> 4) + e;
  dst[idx] = (f16)src[k * 512 + n];            // Wf1 [256][512]
}

// ---------------- feature kernel: fourier + hashgrid + z -> fp16 [B][192] ----
__global__ void feat_kernel(const float* __restrict__ x, const float* __restrict__ z,
                            const float* __restrict__ tables, const int* __restrict__ res,
                            const float* __restrict__ freqs, f16* __restrict__ featsH) {
  __shared__ f16 rowbuf[64][194];
  const int t = threadIdx.x;        // 64 threads
  const int b = blockIdx.x;
  const int i = b * 64 + t;

  float xv = x[i];
  float xn = fminf(fmaxf(xv, 0.f), 1.f);
  f16* dst = rowbuf[t];
  dst[0] = (f16)xn;
  float w2pi = 6.283185307179586f * xn;
  #pragma unroll
  for (int k = 0; k < 32; ++k) {
    float a = w2pi * freqs[k];
    float s, c;
    sincosf(a, &s, &c);
    dst[1 + k]  = (f16)s;
    dst[33 + k] = (f16)c;
  }
  #pragma unroll
  for (int l = 0; l < 8; ++l) {
    int R = res[l];
    int Rm1 = R - 1;
    float tt = xn * (float)Rm1;
    int i0 = (int)tt;
    int i1 = min(i0 + 1, Rm1);
    float w = tt - (float)i0;
    uint32_t lt = (uint32_t)(l * 19349663);
    uint32_t h0 = (((uint32_t)i0 * 73856093u) ^ lt) & 16383u;
    uint32_t h1 = (((uint32_t)i1 * 73856093u) ^ lt) & 16383u;
    const float* e0 = tables + ((size_t)l * 16384 + h0) * 8;
    const float* e1 = tables + ((size_t)l * 16384 + h1) * 8;
    #pragma unroll
    for (int e = 0; e < 8; ++e) {
      float v = e0[e] * (1.f - w) + e1[e] * w;
      dst[65 + l * 8 + e] = (f16)v;
    }
  }
  #pragma unroll
  for (int j = 0; j < 32; ++j) dst[129 + j] = (f16)z[(size_t)i * 32 + j];
  #pragma unroll
  for (int j = 161; j < 192; ++j) dst[j] = (f16)0.f;

  __syncthreads();
  uint32_t* dg = (uint32_t*)(featsH + (size_t)b * 64 * 192);
  for (int idx = t; idx < 64 * 96; idx += 64) {
    int row = idx / 96, o = idx - row * 96;
    dg[idx] = ((const uint32_t*)&rowbuf[row][0])[o];
  }
}

// ---------------- main fused kernel ----------------
// 256 blocks x 512 threads (8 waves), 1 block/CU, 2 waves/SIMD (256 regs).
// R14 base (Wf2 in AGPRs + Wf1 chunk pipeline, 970us) with the stalls removed:
//  * 3 barriers/step (was 5), none drains vmcnt (lgkmcnt-only s_barrier) --
//    R14's __syncthreads flushed the prefetch ring 5x/step.
//  * u double-buffered (uB0/uB1); G2-half0 (pure AGPR MFMA, fence-free) is
//    interleaved INSIDE G1-half1's fenced chunk loop -> every vmcnt/ds_read
//    stall has independent MFMA work behind it.
//  * Region C (G2h1 + tanh epilogue) covers the next step's first chunk.
// Wf1 ring: 2 slots x 16KB, depth 1, vmcnt(2) (2 gloads/chunk/wave).
// Master h = f16 hi (hB) + f16 lo (loB) (R12/R14-verified numerics).
// LDS 160K exact: hB 32K + loB 32K + uB0 32K + uB1 32K + wbuf 32K.
__global__ __launch_bounds__(512)
__attribute__((amdgpu_waves_per_eu(2, 2)))
void fractal_main(
    const f16* __restrict__ featsH,
    const f16* __restrict__ W1L, const f16* __restrict__ W2L,
    const f16* __restrict__ WoL,
    const f16* __restrict__ Wf1C, const f16* __restrict__ Wf2L,
    const float* __restrict__ b1, const float* __restrict__ b2,
    const float* __restrict__ bf1, const float* __restrict__ bf2,
    const float* __restrict__ bo,
    float* __restrict__ out) {
  extern __shared__ char smem[];
  char* hB   = smem;              // 32KB: h hi [64][256] f16 swz (stride 512B)
  char* loB  = smem + 32768;      // 32KB: h lo
  char* uB0  = smem + 65536;      // 32KB: u half0 [64][256] f16 swz (feats staging)
  char* uB1  = smem + 98304;      // 32KB: u half1
  char* wbuf = smem + 131072;     // 32KB: 2 x 16KB Wf1 chunk slots

  const int tid = threadIdx.x;
  const int wn  = tid >> 6;          // 0..7
  const int ln  = tid & 63;
  const int r   = ln & 15;
  const int g   = ln >> 4;
  const int sw  = (r & 7) << 4;
  const int g16 = g * 16;
  const int row0 = blockIdx.x * 64;

  const int cH = 32 * wn + r;        // wave's col base in N=256 ops (+16*nf)
  float b1r[2], b2r[2], bf2r[2], bor[2];
  #pragma unroll
  for (int nf = 0; nf < 2; ++nf) {
    b1r[nf] = b1[cH + 16 * nf]; b2r[nf] = b2[cH + 16 * nf];
    bf2r[nf] = bf2[cH + 16 * nf]; bor[nf] = bo[cH + 16 * nf];
  }
  float bf1r[2][2];                  // [h][nf]
  #pragma unroll
  for (int h = 0; h < 2; ++h)
    #pragma unroll
    for (int nf = 0; nf < 2; ++nf)
      bf1r[h][nf] = bf1[256 * h + cH + 16 * nf];

  const f16* w1b  = W1L  + (2 * wn) * 512 + ln * 8;
  const f16* w2b  = W2L  + (2 * wn) * 512 + ln * 8;
  const f16* wob  = WoL  + (2 * wn) * 512 + ln * 8;
  const f16* wf2b = Wf2L + (2 * wn) * 512 + ln * 8;
  const char* wsrc = (const char*)Wf1C + wn * 2048 + ln * 16;   // +chunk*16384
  char* wdst = wbuf + wn * 2048;                                 // +slot*16384
  const char* wcon = wbuf + wn * 2048 + ln * 16;                 // +slot*16384

  // ---- stage feats tile into uB0 (swizzled, row stride 384B) ----
  {
    const char* src = (const char*)featsH + (size_t)row0 * 384;
    for (int i = tid; i < 6144; i += 512) {
      int row = i / 96;
      int off = (i - row * 96) * 4;
      uint32_t v = *(const uint32_t*)(src + (size_t)i * 4);
      *(uint32_t*)(uB0 + row * 384 + (off ^ ((row & 7) << 4))) = v;
    }
  }
  __syncthreads();

  const f4 zf = {0.f, 0.f, 0.f, 0.f};

  // ---- layer 1: h1 = gelu(feats @ W1 + b1) -> hB ----
  {
    f4 acc[4][2];
    #pragma unroll
    for (int mf = 0; mf < 4; ++mf)
      #pragma unroll
      for (int nf = 0; nf < 2; ++nf) acc[mf][nf] = zf;
    #pragma unroll
    for (int kk = 0; kk < 6; ++kk) {
      h8 bb[2];
      #pragma unroll
      for (int nf = 0; nf < 2; ++nf)
        bb[nf] = *(const h8*)(w1b + ((size_t)(kk * 16 + nf) << 9));
      #pragma unroll
      for (int mf = 0; mf < 4; ++mf) {
        h8 a = *(const h8*)(uB0 + (16 * mf + r) * 384 + ((kk * 64 + g16) ^ sw));
        #pragma unroll
        for (int nf = 0; nf < 2; ++nf)
          acc[mf][nf] = MFMA(a, bb[nf], acc[mf][nf]);
      }
    }
    __syncthreads();   // feats reads done before uB0 reuse
    #pragma unroll
    for (int mf = 0; mf < 4; ++mf)
      #pragma unroll
      for (int nf = 0; nf < 2; ++nf)
        #pragma unroll
        for (int j = 0; j < 4; ++j) {
          float hv = gelu_f(acc[mf][nf][j] + b1r[nf]);
          int row = 16 * mf + g * 4 + j;
          int col = cH + 16 * nf;
          *(f16*)(hB + row * 512 + ((col * 2) ^ ((row & 7) << 4))) = (f16)hv;
        }
  }
  __syncthreads();

  // ---- layer 2: h0 = gelu(h1 @ W2 + b2) -> hB(hi) + loB(lo) ----
  {
    f4 acc[4][2];
    #pragma unroll
    for (int mf = 0; mf < 4; ++mf)
      #pragma unroll
      for (int nf = 0; nf < 2; ++nf) acc[mf][nf] = zf;
    #pragma unroll
    for (int kk = 0; kk < 8; ++kk) {
      h8 bb[2];
      #pragma unroll
      for (int nf = 0; nf < 2; ++nf)
        bb[nf] = *(const h8*)(w2b + ((size_t)(kk * 16 + nf) << 9));
      #pragma unroll
      for (int mf = 0; mf < 4; ++mf) {
        h8 a = *(const h8*)(hB + (16 * mf + r) * 512 + ((kk * 64 + g16) ^ sw));
        #pragma unroll
        for (int nf = 0; nf < 2; ++nf)
          acc[mf][nf] = MFMA(a, bb[nf], acc[mf][nf]);
      }
    }
    __syncthreads();   // h1 reads done before overwrite
    #pragma unroll
    for (int mf = 0; mf < 4; ++mf)
      #pragma unroll
      for (int nf = 0; nf < 2; ++nf)
        #pragma unroll
        for (int j = 0; j < 4; ++j) {
          float hv = gelu_f(acc[mf][nf][j] + b2r[nf]);
          int row = 16 * mf + g * 4 + j;
          int col = cH + 16 * nf;
          int so = (col * 2) ^ ((row & 7) << 4);
          f16 hi = (f16)hv;
          *(f16*)(hB + row * 512 + so) = hi;
          *(f16*)(loB + row * 512 + so) = (f16)(hv - (float)hi);
        }
  }
  __syncthreads();

  // ---- Wf2 wave slice -> AGPRs (R13/R14-verified mechanism) ----
  h8 wB[16][2];
  #pragma unroll
  for (int kk = 0; kk < 16; ++kk)
    #pragma unroll
    for (int nf = 0; nf < 2; ++nf) {
      wB[kk][nf] = *(const h8*)(wf2b + ((size_t)(kk * 16 + nf) << 9));
      asm("" : "+a"(wB[kk][nf]));
    }

  // ---- chunk-ring prologue: issue chunk 0 into slot 0 ----
  gload_lds16(wsrc, wdst);
  gload_lds16(wsrc + 1024, wdst + 1024);

  // ---- 48 fractal steps, 3 barriers/step ----
  #pragma unroll 1
  for (int t = 0; t < TSTEPS; ++t) {
    f4 a2[4][2];
    #pragma unroll
    for (int mf = 0; mf < 4; ++mf)
      #pragma unroll
      for (int nf = 0; nf < 2; ++nf) a2[mf][nf] = zf;

    // ===== region A: G1h0 -> uB0 =====
    {
      f4 a1[4][2];
      #pragma unroll
      for (int mf = 0; mf < 4; ++mf)
        #pragma unroll
        for (int nf = 0; nf < 2; ++nf) a1[mf][nf] = zf;
      #pragma unroll
      for (int kk = 0; kk < 8; ++kk) {
        const int o = kk;
        gload_lds16(wsrc + (((o + 1) & 15) << 14), wdst + (((o + 1) & 1) << 14));
        gload_lds16(wsrc + (((o + 1) & 15) << 14) + 1024,
                    wdst + (((o + 1) & 1) << 14) + 1024);
        asm volatile("s_waitcnt vmcnt(2)" ::: "memory");
        __builtin_amdgcn_sched_barrier(0);
        const char* wb = wcon + ((o & 1) << 14);
        h8 bb0 = *(const h8*)(wb);
        h8 bb1 = *(const h8*)(wb + 1024);
        #pragma unroll
        for (int mf = 0; mf < 4; ++mf) {
          h8 a = *(const h8*)(hB + (16 * mf + r) * 512 + ((kk * 64 + g16) ^ sw));
          a1[mf][0] = MFMA(a, bb0, a1[mf][0]);
          a1[mf][1] = MFMA(a, bb1, a1[mf][1]);
        }
      }
      #pragma unroll
      for (int mf = 0; mf < 4; ++mf)
        #pragma unroll
        for (int nf = 0; nf < 2; ++nf)
          #pragma unroll
          for (int j = 0; j < 4; ++j) {
            float gv = gelu_f(a1[mf][nf][j] + bf1r[0][nf]);
            int row = 16 * mf + g * 4 + j;
            int col = cH + 16 * nf;
            *(f16*)(uB0 + row * 512 + ((col * 2) ^ ((row & 7) << 4))) = (f16)gv;
          }
    }
    barrier_lds();

    // ===== region B: G2h0 (AGPR, fence-free) interleaved with G1h1 =====
    {
      f4 a1[4][2];
      #pragma unroll
      for (int mf = 0; mf < 4; ++mf)
        #pragma unroll
        for (int nf = 0; nf < 2; ++nf) a1[mf][nf] = zf;
      #pragma unroll
      for (int kk = 0; kk < 8; ++kk) {
        const int o = 8 + kk;
        gload_lds16(wsrc + (((o + 1) & 15) << 14), wdst + (((o + 1) & 1) << 14));
        gload_lds16(wsrc + (((o + 1) & 15) << 14) + 1024,
                    wdst + (((o + 1) & 1) << 14) + 1024);
        asm volatile("s_waitcnt vmcnt(2)" ::: "memory");
        __builtin_amdgcn_sched_barrier(0);
        const char* wb = wcon + ((o & 1) << 14);
        h8 bb0 = *(const h8*)(wb);
        h8 bb1 = *(const h8*)(wb + 1024);
        #pragma unroll
        for (int mf = 0; mf < 4; ++mf) {
          h8 aH = *(const h8*)(hB + (16 * mf + r) * 512 + ((kk * 64 + g16) ^ sw));
          a1[mf][0] = MFMA(aH, bb0, a1[mf][0]);
          a1[mf][1] = MFMA(aH, bb1, a1[mf][1]);
          h8 aU = *(const h8*)(uB0 + (16 * mf + r) * 512 + ((kk * 64 + g16) ^ sw));
          MFMA_AB(a2[mf][0], aU, wB[kk][0]);
          MFMA_AB(a2[mf][1], aU, wB[kk][1]);
        }
      }
      #pragma unroll
      for (int mf = 0; mf < 4; ++mf)
        #pragma unroll
        for (int nf = 0; nf < 2; ++nf)
          #pragma unroll
          for (int j = 0; j < 4; ++j) {
            float gv = gelu_f(a1[mf][nf][j] + bf1r[1][nf]);
            int row = 16 * mf + g * 4 + j;
            int col = cH + 16 * nf;
            *(f16*)(uB1 + row * 512 + ((col * 2) ^ ((row & 7) << 4))) = (f16)gv;
          }
    }
    barrier_lds();

    // ===== region C: G2h1 (AGPR) + step epilogue =====
    #pragma unroll
    for (int kk = 0; kk < 8; ++kk) {
      #pragma unroll
      for (int mf = 0; mf < 4; ++mf) {
        h8 aU = *(const h8*)(uB1 + (16 * mf + r) * 512 + ((kk * 64 + g16) ^ sw));
        MFMA_AB(a2[mf][0], aU, wB[8 + kk][0]);
        MFMA_AB(a2[mf][1], aU, wB[8 + kk][1]);
      }
    }
    #pragma unroll
    for (int mf = 0; mf < 4; ++mf)
      #pragma unroll
      for (int nf = 0; nf < 2; ++nf)
        #pragma unroll
        for (int j = 0; j < 4; ++j) {
          int row = 16 * mf + g * 4 + j;
          int col = cH + 16 * nf;
          int so = (col * 2) ^ ((row & 7) << 4);
          f16* hp = (f16*)(hB + row * 512 + so);
          f16* lp = (f16*)(loB + row * 512 + so);
          float mval = (float)*hp + (float)*lp;
          float u = tanh_f(a2[mf][nf][j] + bf2r[nf]);
          float hn = 0.5f * (mval + u);
          f16 hi = (f16)hn;
          *hp = hi;
          *lp = (f16)(hn - (float)hi);
        }
    barrier_lds();
  }

  // ---- final: out = h @ Wo + bo ----
  {
    f4 acc[4][2];
    #pragma unroll
    for (int mf = 0; mf < 4; ++mf)
      #pragma unroll
      for (int nf = 0; nf < 2; ++nf) acc[mf][nf] = zf;
    #pragma unroll
    for (int kk = 0; kk < 8; ++kk) {
      h8 bb[2];
      #pragma unroll
      for (int nf = 0; nf < 2; ++nf)
        bb[nf] = *(const h8*)(wob + ((size_t)(kk * 16 + nf) << 9));
      #pragma unroll
      for (int mf = 0; mf < 4; ++mf) {
        h8 a = *(const h8*)(hB + (16 * mf + r) * 512 + ((kk * 64 + g16) ^ sw));
        #pragma unroll
        for (int nf = 0; nf < 2; ++nf)
          acc[mf][nf] = MFMA(a, bb[nf], acc[mf][nf]);
      }
    }
    #pragma unroll
    for (int mf = 0; mf < 4; ++mf)
      #pragma unroll
      for (int nf = 0; nf < 2; ++nf)
        #pragma unroll
        for (int j = 0; j < 4; ++j) {
          int row = row0 + 16 * mf + g * 4 + j;
          int col = cH + 16 * nf;
          out[(size_t)row * 256 + col] = acc[mf][nf][j] + bor[nf];
        }
  }
}

// ---------------- host launch ----------------
extern "C" void kernel_launch(void* const* d_in, const int* in_sizes, int n_in,
                              void* d_out, int out_size, void* d_ws, size_t ws_size,
                              hipStream_t stream) {
  const float* x      = (const float*)d_in[0];
  const float* z      = (const float*)d_in[1];
  const float* tables = (const float*)d_in[2];
  const float* W1     = (const float*)d_in[3];
  const float* b1     = (const float*)d_in[4];
  const float* W2     = (const float*)d_in[5];
  const float* b2     = (const float*)d_in[6];
  const float* Wf1    = (const float*)d_in[7];
  const float* bf1    = (const float*)d_in[8];
  const float* Wf2    = (const float*)d_in[9];
  const float* bf2    = (const float*)d_in[10];
  const float* Wo     = (const float*)d_in[11];
  const float* bo     = (const float*)d_in[12];
  const int*   res    = (const int*)d_in[13];
  const float* freqs  = (const float*)d_in[14];
  float* out = (float*)d_out;

  char* ws = (char*)d_ws;
  f16* featsH = (f16*)(ws);                 // 16384*192*2 = 6291456
  f16* W1L    = (f16*)(ws + 6291456);       // 98304
  f16* W2L    = (f16*)(ws + 6389760);       // 131072
  f16* WoL    = (f16*)(ws + 6520832);       // 131072
  f16* Wf1C   = (f16*)(ws + 6651904);       // 262144 (16 x 16KB chunks)
  f16* Wf2L   = (f16*)(ws + 6914048);       // 262144 (lane-linear frags)

  prep_lin<<<192, 256, 0, stream>>>(W1,  W1L,  161, 256, 96  * 512);
  prep_lin<<<256, 256, 0, stream>>>(W2,  W2L,  256, 256, 128 * 512);
  prep_lin<<<256, 256, 0, stream>>>(Wo,  WoL,  256, 256, 128 * 512);
  prep_wf1c<<<512, 256, 0, stream>>>(Wf1, Wf1C);
  prep_lin<<<512, 256, 0, stream>>>(Wf2, Wf2L, 512, 256, 256 * 512);
  feat_kernel<<<256, 64, 0, stream>>>(x, z, tables, res, freqs, featsH);

  (void)hipFuncSetAttribute((const void*)fractal_main,
                            hipFuncAttributeMaxDynamicSharedMemorySize, 163840);
  fractal_main<<<256, 512, 163840, stream>>>(featsH, W1L, W2L, WoL, Wf1C, Wf2L,
                                             b1, b2, bf1, bf2, bo, out);
}

// Round 17
// 958.422 us; speedup vs baseline: 1.6204x; 1.6204x over previous
//
#include <hip/hip_runtime.h>
#include <hip/hip_fp16.h>
#include <math.h>
#include <stdint.h>

typedef _Float16 f16;
typedef _Float16 h8 __attribute__((ext_vector_type(8)));
typedef float f4 __attribute__((ext_vector_type(4)));

#define TSTEPS 48

#define MFMA(a,b,c) __builtin_amdgcn_mfma_f32_16x16x32_f16((a),(b),(c),0,0,0)
// inline-asm MFMA with acc and B pinned to the AGPR half of the unified file
#define MFMA_AB(acc, a, b) \
  asm("v_mfma_f32_16x16x32_f16 %0, %1, %2, %0" : "+a"(acc) : "v"(a), "a"(b))

__device__ __forceinline__ float gelu_f(float x) {
  float ax = fabsf(x) * 0.7071067811865475f;
  float t = __builtin_amdgcn_rcpf(1.0f + 0.3275911f * ax);
  float poly = t * (0.254829592f + t * (-0.284496736f + t * (1.421413741f +
               t * (-1.453152027f + t * 1.061405429f))));
  float e = exp2f(-ax * ax * 1.4426950408889634f);
  float er = copysignf(1.0f - poly * e, x);
  return 0.5f * x * (1.0f + er);
}

__device__ __forceinline__ float tanh_f(float x) {
  float e = exp2f(x * 2.885390081777927f);
  return 1.0f - 2.0f * __builtin_amdgcn_rcpf(e + 1.0f);
}

__device__ __forceinline__ void gload_lds16(const void* g, void* l) {
  __builtin_amdgcn_global_load_lds(
      (const __attribute__((address_space(1))) void*)g,
      (__attribute__((address_space(3))) void*)l, 16, 0, 0);
}

// ---------------- unified lane-linear weight prep (W1/W2/Wo/Wf2) ----------------
// Fragment (kk, cf): 16 cols c0=cf*16, 32 k's at kk*32. Lane ln holds 8 f16:
// dst[fragid*512 + ln*8 + e] = src[(kk*32 + (ln>>4)*8 + e) * N + cf*16 + (ln&15)]
__global__ void prep_lin(const float* __restrict__ src, f16* __restrict__ dst,
                         int Kreal, int N, int total) {
  int idx = blockIdx.x * 256 + threadIdx.x;
  if (idx >= total) return;
  int fragid = idx >> 9;
  int within = idx & 511;
  int ln = within >> 3, e = within & 7;
  int nfr = N >> 4;
  int kk = fragid / nfr, cf = fragid - kk * nfr;
  int k = kk * 32 + ((ln >> 4) << 3) + e;
  int n = (cf << 4) + (ln & 15);
  dst[idx] = (f16)((k < Kreal) ? src[k * N + n] : 0.f);
}

// ---------------- Wf1 chunk stream: 16 chunks of 16KB ----------------
// chunk c = (h*8 + kk): k-slice [32kk,+32) x cols [256h,+256) as 16 lane-linear
// 1KB frags (frag cf: cols [256h+16cf,+16)).
__global__ void prep_wf1c(const float* __restrict__ src, f16* __restrict__ dst) {
  int idx = blockIdx.x * 256 + threadIdx.x;    // 131072
  if (idx >= 131072) return;
  int f = idx >> 9, w = idx & 511;
  int ln = w >> 3, e = w & 7;
  int cf = f & 15, kk = (f >> 4) & 7, h = f >> 7;
  int n = 256 * h + 16 * cf + (ln & 15);
  int k = 32 * kk + 8 * (ln >> 4) + e;
  dst[idx] = (f16)src[k * 512 + n];            // Wf1 [256][512]
}

// ---------------- feature kernel: fourier + hashgrid + z -> fp16 [B][192] ----
__global__ void feat_kernel(const float* __restrict__ x, const float* __restrict__ z,
                            const float* __restrict__ tables, const int* __restrict__ res,
                            const float* __restrict__ freqs, f16* __restrict__ featsH) {
  __shared__ f16 rowbuf[64][194];
  const int t = threadIdx.x;        // 64 threads
  const int b = blockIdx.x;
  const int i = b * 64 + t;

  float xv = x[i];
  float xn = fminf(fmaxf(xv, 0.f), 1.f);
  f16* dst = rowbuf[t];
  dst[0] = (f16)xn;
  float w2pi = 6.283185307179586f * xn;
  #pragma unroll
  for (int k = 0; k < 32; ++k) {
    float a = w2pi * freqs[k];
    float s, c;
    sincosf(a, &s, &c);
    dst[1 + k]  = (f16)s;
    dst[33 + k] = (f16)c;
  }
  #pragma unroll
  for (int l = 0; l < 8; ++l) {
    int R = res[l];
    int Rm1 = R - 1;
    float tt = xn * (float)Rm1;
    int i0 = (int)tt;
    int i1 = min(i0 + 1, Rm1);
    float w = tt - (float)i0;
    uint32_t lt = (uint32_t)(l * 19349663);
    uint32_t h0 = (((uint32_t)i0 * 73856093u) ^ lt) & 16383u;
    uint32_t h1 = (((uint32_t)i1 * 73856093u) ^ lt) & 16383u;
    const float* e0 = tables + ((size_t)l * 16384 + h0) * 8;
    const float* e1 = tables + ((size_t)l * 16384 + h1) * 8;
    #pragma unroll
    for (int e = 0; e < 8; ++e) {
      float v = e0[e] * (1.f - w) + e1[e] * w;
      dst[65 + l * 8 + e] = (f16)v;
    }
  }
  #pragma unroll
  for (int j = 0; j < 32; ++j) dst[129 + j] = (f16)z[(size_t)i * 32 + j];
  #pragma unroll
  for (int j = 161; j < 192; ++j) dst[j] = (f16)0.f;

  __syncthreads();
  uint32_t* dg = (uint32_t*)(featsH + (size_t)b * 64 * 192);
  for (int idx = t; idx < 64 * 96; idx += 64) {
    int row = idx / 96, o = idx - row * 96;
    dg[idx] = ((const uint32_t*)&rowbuf[row][0])[o];
  }
}

// ---------------- main fused kernel ----------------
// R14 (970us verified best) + two safe deltas:
//  1. Wf1 chunk ring 3->4 slots (LDS 160K), depth 2->3, vmcnt(6) -> smoother
//     refill after each drain-barrier.
//  2. after-G2h1 barrier removed (5->4/step) -- desk-checked: no hB/loB reader
//     and no uB writer exists between it and the step-epilogue barrier.
// KEPT: full-drain __syncthreads (they synchronize the 32 CUs/XCD onto the
// same stream window -> 77% L2 hit in R14; R16 proved removing them kills it),
// AGPR-pinned Wf2 (R13), wave-private chunk staging (R14), hi/lo master h.
// 256 blocks x 512 threads (8 waves), 1 block/CU, 2 waves/SIMD (256 regs).
// LDS 160K exact: hB 32K + uB 32K + loB 32K + wbuf 64K (4 x 16KB slots).
__global__ __launch_bounds__(512)
__attribute__((amdgpu_waves_per_eu(2, 2)))
void fractal_main(
    const f16* __restrict__ featsH,
    const f16* __restrict__ W1L, const f16* __restrict__ W2L,
    const f16* __restrict__ WoL,
    const f16* __restrict__ Wf1C, const f16* __restrict__ Wf2L,
    const float* __restrict__ b1, const float* __restrict__ b2,
    const float* __restrict__ bf1, const float* __restrict__ bf2,
    const float* __restrict__ bo,
    float* __restrict__ out) {
  extern __shared__ char smem[];
  char* hB   = smem;             // 32KB: h hi [64][256] f16 swz
  char* uB   = smem + 32768;     // 32KB: u half [64][256] f16 swz (feats staging)
  char* loB  = smem + 65536;     // 32KB: h lo
  char* wbuf = smem + 98304;     // 64KB: 4 x 16KB Wf1 chunk slots

  const int tid = threadIdx.x;
  const int wn  = tid >> 6;          // 0..7
  const int ln  = tid & 63;
  const int r   = ln & 15;
  const int g   = ln >> 4;
  const int sw  = (r & 7) << 4;
  const int g16 = g * 16;
  const int row0 = blockIdx.x * 64;

  const int cH = 32 * wn + r;        // wave's col base in N=256 ops (+16*nf)
  float b1r[2], b2r[2], bf2r[2], bor[2];
  #pragma unroll
  for (int nf = 0; nf < 2; ++nf) {
    b1r[nf] = b1[cH + 16 * nf]; b2r[nf] = b2[cH + 16 * nf];
    bf2r[nf] = bf2[cH + 16 * nf]; bor[nf] = bo[cH + 16 * nf];
  }
  float bf1r[2][2];                  // [h][nf]: GEMM1 col = 256h + 32wn+16nf+r
  #pragma unroll
  for (int h = 0; h < 2; ++h)
    #pragma unroll
    for (int nf = 0; nf < 2; ++nf)
      bf1r[h][nf] = bf1[256 * h + cH + 16 * nf];

  const f16* w1b  = W1L  + (2 * wn) * 512 + ln * 8;
  const f16* w2b  = W2L  + (2 * wn) * 512 + ln * 8;
  const f16* wob  = WoL  + (2 * wn) * 512 + ln * 8;
  const f16* wf2b = Wf2L + (2 * wn) * 512 + ln * 8;

  // ---- stage feats tile into uB (swizzled, row stride 384B) ----
  {
    const char* src = (const char*)featsH + (size_t)row0 * 384;
    for (int i = tid; i < 6144; i += 512) {
      int row = i / 96;
      int off = (i - row * 96) * 4;
      uint32_t v = *(const uint32_t*)(src + (size_t)i * 4);
      *(uint32_t*)(uB + row * 384 + (off ^ ((row & 7) << 4))) = v;
    }
  }
  __syncthreads();

  const f4 zf = {0.f, 0.f, 0.f, 0.f};

  // ---- layer 1: h1 = gelu(feats @ W1 + b1) -> hB ----
  {
    f4 acc[4][2];
    #pragma unroll
    for (int mf = 0; mf < 4; ++mf)
      #pragma unroll
      for (int nf = 0; nf < 2; ++nf) acc[mf][nf] = zf;
    #pragma unroll
    for (int kk = 0; kk < 6; ++kk) {
      h8 bb[2];
      #pragma unroll
      for (int nf = 0; nf < 2; ++nf)
        bb[nf] = *(const h8*)(w1b + ((size_t)(kk * 16 + nf) << 9));
      #pragma unroll
      for (int mf = 0; mf < 4; ++mf) {
        h8 a = *(const h8*)(uB + (16 * mf + r) * 384 + ((kk * 64 + g16) ^ sw));
        #pragma unroll
        for (int nf = 0; nf < 2; ++nf)
          acc[mf][nf] = MFMA(a, bb[nf], acc[mf][nf]);
      }
    }
    __syncthreads();   // uB (feats) reads done
    #pragma unroll
    for (int mf = 0; mf < 4; ++mf)
      #pragma unroll
      for (int nf = 0; nf < 2; ++nf)
        #pragma unroll
        for (int j = 0; j < 4; ++j) {
          float hv = gelu_f(acc[mf][nf][j] + b1r[nf]);
          int row = 16 * mf + g * 4 + j;
          int col = cH + 16 * nf;
          *(f16*)(hB + row * 512 + ((col * 2) ^ ((row & 7) << 4))) = (f16)hv;
        }
  }
  __syncthreads();

  // ---- layer 2: h0 = gelu(h1 @ W2 + b2) -> hB(hi) + loB(lo) ----
  {
    f4 acc[4][2];
    #pragma unroll
    for (int mf = 0; mf < 4; ++mf)
      #pragma unroll
      for (int nf = 0; nf < 2; ++nf) acc[mf][nf] = zf;
    #pragma unroll
    for (int kk = 0; kk < 8; ++kk) {
      h8 bb[2];
      #pragma unroll
      for (int nf = 0; nf < 2; ++nf)
        bb[nf] = *(const h8*)(w2b + ((size_t)(kk * 16 + nf) << 9));
      #pragma unroll
      for (int mf = 0; mf < 4; ++mf) {
        h8 a = *(const h8*)(hB + (16 * mf + r) * 512 + ((kk * 64 + g16) ^ sw));
        #pragma unroll
        for (int nf = 0; nf < 2; ++nf)
          acc[mf][nf] = MFMA(a, bb[nf], acc[mf][nf]);
      }
    }
    __syncthreads();   // h1 reads done before overwrite
    #pragma unroll
    for (int mf = 0; mf < 4; ++mf)
      #pragma unroll
      for (int nf = 0; nf < 2; ++nf)
        #pragma unroll
        for (int j = 0; j < 4; ++j) {
          float hv = gelu_f(acc[mf][nf][j] + b2r[nf]);
          int row = 16 * mf + g * 4 + j;
          int col = cH + 16 * nf;
          int so = (col * 2) ^ ((row & 7) << 4);
          f16 hi = (f16)hv;
          *(f16*)(hB + row * 512 + so) = hi;
          *(f16*)(loB + row * 512 + so) = (f16)(hv - (float)hi);
        }
  }
  __syncthreads();

  // ---- Wf2 wave slice -> AGPRs (R13/R14-verified mechanism) ----
  h8 wB[16][2];
  #pragma unroll
  for (int kk = 0; kk < 16; ++kk)
    #pragma unroll
    for (int nf = 0; nf < 2; ++nf) {
      wB[kk][nf] = *(const h8*)(wf2b + ((size_t)(kk * 16 + nf) << 9));
      asm("" : "+a"(wB[kk][nf]));
    }

  // ---- Wf1 chunk pipeline prologue: issue chunks 0,1,2 (depth 3) ----
  const char* wsrc = (const char*)Wf1C + wn * 2048 + ln * 16;
  char* wdst = wbuf + wn * 2048;
  #pragma unroll
  for (int c = 0; c < 3; ++c) {
    gload_lds16(wsrc + c * 16384, wdst + c * 16384);
    gload_lds16(wsrc + c * 16384 + 1024, wdst + c * 16384 + 1024);
  }
  int iad = 3, isl = 3, csl = 0;   // issue addr-chunk, issue slot, consume slot

  // ---- 48 fractal steps, 4 barriers/step ----
  #pragma unroll 1
  for (int t = 0; t < TSTEPS; ++t) {
    f4 a2[4][2];
    #pragma unroll
    for (int mf = 0; mf < 4; ++mf)
      #pragma unroll
      for (int nf = 0; nf < 2; ++nf) a2[mf][nf] = zf;

    #pragma unroll
    for (int h = 0; h < 2; ++h) {
      // GEMM1 half h: u_h = gelu(hB @ Wf1[:,256h:+256] + bf1)
      f4 a1[4][2];
      #pragma unroll
      for (int mf = 0; mf < 4; ++mf)
        #pragma unroll
        for (int nf = 0; nf < 2; ++nf) a1[mf][nf] = zf;
      #pragma unroll 1
      for (int kk = 0; kk < 8; ++kk) {
        // issue chunk iad (depth 3; never drained by hand in-loop)
        gload_lds16(wsrc + iad * 16384, wdst + isl * 16384);
        gload_lds16(wsrc + iad * 16384 + 1024, wdst + isl * 16384 + 1024);
        iad = (iad + 1) & 15;
        isl = (isl + 1) & 3;
        asm volatile("s_waitcnt vmcnt(6)" ::: "memory");
        __builtin_amdgcn_sched_barrier(0);
        const char* wb = wbuf + csl * 16384 + (2 * wn) * 1024 + ln * 16;
        csl = (csl + 1) & 3;
        h8 bb0 = *(const h8*)(wb);
        h8 bb1 = *(const h8*)(wb + 1024);
        #pragma unroll
        for (int mf = 0; mf < 4; ++mf) {
          h8 a = *(const h8*)(hB + (16 * mf + r) * 512 + ((kk * 64 + g16) ^ sw));
          a1[mf][0] = MFMA(a, bb0, a1[mf][0]);
          a1[mf][1] = MFMA(a, bb1, a1[mf][1]);
        }
      }
      // epilogue half: gelu -> uB ([64][256], stride 512B, swz)
      #pragma unroll
      for (int mf = 0; mf < 4; ++mf)
        #pragma unroll
        for (int nf = 0; nf < 2; ++nf)
          #pragma unroll
          for (int j = 0; j < 4; ++j) {
            float gv = gelu_f(a1[mf][nf][j] + bf1r[h][nf]);
            int row = 16 * mf + g * 4 + j;
            int col = cH + 16 * nf;
            *(f16*)(uB + row * 512 + ((col * 2) ^ ((row & 7) << 4))) = (f16)gv;
          }
      __syncthreads();

      // GEMM2 partial: a2 += u_h @ Wf2[256h:+256,:]  (B in AGPRs, zero loads)
      #pragma unroll
      for (int kk2 = 0; kk2 < 8; ++kk2) {
        #pragma unroll
        for (int mf = 0; mf < 4; ++mf) {
          h8 a = *(const h8*)(uB + (16 * mf + r) * 512 + ((kk2 * 64 + g16) ^ sw));
          MFMA_AB(a2[mf][0], a, wB[8 * h + kk2][0]);
          MFMA_AB(a2[mf][1], a, wB[8 * h + kk2][1]);
        }
      }
      if (h == 0) __syncthreads();   // uB reads done before half1 overwrites;
                                     // after half1 no uB write until next step's
                                     // G1h0 epilogue (behind step barrier) -> no
                                     // barrier needed here (R17 delta 2)
    }

    // step epilogue: m = hi+lo; h' = 0.5*(m + tanh(a2+bf2)); write hi/lo
    #pragma unroll
    for (int mf = 0; mf < 4; ++mf)
      #pragma unroll
      for (int nf = 0; nf < 2; ++nf)
        #pragma unroll
        for (int j = 0; j < 4; ++j) {
          int row = 16 * mf + g * 4 + j;
          int col = cH + 16 * nf;
          int so = (col * 2) ^ ((row & 7) << 4);
          f16* hp = (f16*)(hB + row * 512 + so);
          f16* lp = (f16*)(loB + row * 512 + so);
          float mval = (float)*hp + (float)*lp;
          float u = tanh_f(a2[mf][nf][j] + bf2r[nf]);
          float hn = 0.5f * (mval + u);
          f16 hi = (f16)hn;
          *hp = hi;
          *lp = (f16)(hn - (float)hi);
        }
    __syncthreads();
  }

  // ---- final: out = h @ Wo + bo ----
  {
    f4 acc[4][2];
    #pragma unroll
    for (int mf = 0; mf < 4; ++mf)
      #pragma unroll
      for (int nf = 0; nf < 2; ++nf) acc[mf][nf] = zf;
    #pragma unroll
    for (int kk = 0; kk < 8; ++kk) {
      h8 bb[2];
      #pragma unroll
      for (int nf = 0; nf < 2; ++nf)
        bb[nf] = *(const h8*)(wob + ((size_t)(kk * 16 + nf) << 9));
      #pragma unroll
      for (int mf = 0; mf < 4; ++mf) {
        h8 a = *(const h8*)(hB + (16 * mf + r) * 512 + ((kk * 64 + g16) ^ sw));
        #pragma unroll
        for (int nf = 0; nf < 2; ++nf)
          acc[mf][nf] = MFMA(a, bb[nf], acc[mf][nf]);
      }
    }
    #pragma unroll
    for (int mf = 0; mf < 4; ++mf)
      #pragma unroll
      for (int nf = 0; nf < 2; ++nf)
        #pragma unroll
        for (int j = 0; j < 4; ++j) {
          int row = row0 + 16 * mf + g * 4 + j;
          int col = cH + 16 * nf;
          out[(size_t)row * 256 + col] = acc[mf][nf][j] + bor[nf];
        }
  }
}

// ---------------- host launch ----------------
extern "C" void kernel_launch(void* const* d_in, const int* in_sizes, int n_in,
                              void* d_out, int out_size, void* d_ws, size_t ws_size,
                              hipStream_t stream) {
  const float* x      = (const float*)d_in[0];
  const float* z      = (const float*)d_in[1];
  const float* tables = (const float*)d_in[2];
  const float* W1     = (const float*)d_in[3];
  const float* b1     = (const float*)d_in[4];
  const float* W2     = (const float*)d_in[5];
  const float* b2     = (const float*)d_in[6];
  const float* Wf1    = (const float*)d_in[7];
  const float* bf1    = (const float*)d_in[8];
  const float* Wf2    = (const float*)d_in[9];
  const float* bf2    = (const float*)d_in[10];
  const float* Wo     = (const float*)d_in[11];
  const float* bo     = (const float*)d_in[12];
  const int*   res    = (const int*)d_in[13];
  const float* freqs  = (const float*)d_in[14];
  float* out = (float*)d_out;

  char* ws = (char*)d_ws;
  f16* featsH = (f16*)(ws);                 // 16384*192*2 = 6291456
  f16* W1L    = (f16*)(ws + 6291456);       // 98304
  f16* W2L    = (f16*)(ws + 6389760);       // 131072
  f16* WoL    = (f16*)(ws + 6520832);       // 131072
  f16* Wf1C   = (f16*)(ws + 6651904);       // 262144 (16 x 16KB chunks)
  f16* Wf2L   = (f16*)(ws + 6914048);       // 262144 (lane-linear frags)

  prep_lin<<<192, 256, 0, stream>>>(W1,  W1L,  161, 256, 96  * 512);
  prep_lin<<<256, 256, 0, stream>>>(W2,  W2L,  256, 256, 128 * 512);
  prep_lin<<<256, 256, 0, stream>>>(Wo,  WoL,  256, 256, 128 * 512);
  prep_wf1c<<<512, 256, 0, stream>>>(Wf1, Wf1C);
  prep_lin<<<512, 256, 0, stream>>>(Wf2, Wf2L, 512, 256, 256 * 512);
  feat_kernel<<<256, 64, 0, stream>>>(x, z, tables, res, freqs, featsH);

  (void)hipFuncSetAttribute((const void*)fractal_main,
                            hipFuncAttributeMaxDynamicSharedMemorySize, 163840);
  fractal_main<<<256, 512, 163840, stream>>>(featsH, W1L, W2L, WoL, Wf1C, Wf2L,
                                             b1, b2, bf1, bf2, bo, out);
}